// Round 2
// baseline (132.775 us; speedup 1.0000x reference)
//
#include <hip/hip_runtime.h>

#define NB 4
#define LQ 512
#define LK 512
#define EE 128
#define DD 256

__device__ __forceinline__ float fast_rcp(float x) { return __builtin_amdgcn_rcpf(x); }

// K1: rows 0..2047 = query@Wc1 -> Eq=exp(2q); rows 2048..4095 = key@Wc2 -> Ek=exp(2k)
// 8 rows per block, 256 threads (2 col-groups x 128 cols), 4 rows/thread register blocking.
// Eq/Ek are stored in the ctx region of d_out (exactly 2*262144 floats); K3 later
// overwrites that region AFTER K2 has consumed Eq/Ek (stream-ordered).
__global__ __launch_bounds__(256) void proj_exp_kernel(
    const float* __restrict__ query, const float* __restrict__ key,
    const float* __restrict__ Wc1, const float* __restrict__ Wc2,
    float* __restrict__ Eq, float* __restrict__ Ek)
{
    __shared__ float in_s[8][DD];
    const int r0 = blockIdx.x * 8;
    const float* src; const float* W; float* dst; int rbase;
    if (r0 < NB * LQ) { src = query; W = Wc1; dst = Eq; rbase = r0; }
    else              { src = key;   W = Wc2; dst = Ek; rbase = r0 - NB * LQ; }
    const float* srow = src + (size_t)rbase * DD;
    #pragma unroll
    for (int i = 0; i < 8; ++i)
        ((float*)in_s)[i * 256 + threadIdx.x] = srow[i * 256 + threadIdx.x];
    __syncthreads();
    const int c  = threadIdx.x & 127;
    const int rg = threadIdx.x >> 7;   // 0..1, rows rg*4 .. rg*4+3
    float acc[4] = {0.f, 0.f, 0.f, 0.f};
    for (int d = 0; d < DD; d += 4) {
        const float w0 = W[(d + 0) * EE + c];
        const float w1 = W[(d + 1) * EE + c];
        const float w2 = W[(d + 2) * EE + c];
        const float w3 = W[(d + 3) * EE + c];
        #pragma unroll
        for (int i = 0; i < 4; ++i) {
            const float4 x = *(const float4*)&in_s[rg * 4 + i][d];  // wave-uniform addr -> LDS broadcast
            acc[i] += x.x * w0 + x.y * w1 + x.z * w2 + x.w * w3;
        }
    }
    #pragma unroll
    for (int i = 0; i < 4; ++i)
        dst[(size_t)(rbase + rg * 4 + i) * EE + c] = __expf(2.0f * acc[i]);
}

// K2: per block (b, l-tile of 4): sjt for all 512 q via tanh(x)=1-2/(e^{2x}+1),
// softmax over q, write atten. Thread owns q=tid and q=tid+256.
__global__ __launch_bounds__(256) void atten_kernel(
    const float* __restrict__ Eq, const float* __restrict__ Ek,
    const float* __restrict__ vc, float* __restrict__ attn)
{
    __shared__ float sj_s[4][LQ];
    __shared__ float rinv_s[4];
    const int b   = blockIdx.x >> 7;
    const int lt  = blockIdx.x & 127;
    const int l0  = lt * 4;
    const int tid = threadIdx.x;
    const float* eqb = Eq + (size_t)b * LQ * EE;
    const float* ekb = Ek + ((size_t)b * LK + l0) * EE;

    // sum of vc (uniform loads -> scalar cache)
    float vcsum = 0.f;
    for (int e = 0; e < EE; e += 4) {
        const float4 v = *(const float4*)(vc + e);
        vcsum += (v.x + v.y) + (v.z + v.w);
    }

    // phase 1: s2[qq][l] = sum_e vc_e / (Eq*Ek + 1)
    float s2[2][4] = {{0.f,0.f,0.f,0.f},{0.f,0.f,0.f,0.f}};
    const float* eq0 = eqb + (size_t)tid * EE;
    const float* eq1 = eqb + (size_t)(tid + 256) * EE;
    for (int e = 0; e < EE; e += 4) {
        const float4 a0 = *(const float4*)(eq0 + e);
        const float4 a1 = *(const float4*)(eq1 + e);
        const float4 vv = *(const float4*)(vc + e);     // uniform
        #pragma unroll
        for (int l = 0; l < 4; ++l) {
            const float4 kk = *(const float4*)(ekb + l * EE + e);  // uniform
            s2[0][l] += vv.x * fast_rcp(a0.x * kk.x + 1.0f);
            s2[0][l] += vv.y * fast_rcp(a0.y * kk.y + 1.0f);
            s2[0][l] += vv.z * fast_rcp(a0.z * kk.z + 1.0f);
            s2[0][l] += vv.w * fast_rcp(a0.w * kk.w + 1.0f);
            s2[1][l] += vv.x * fast_rcp(a1.x * kk.x + 1.0f);
            s2[1][l] += vv.y * fast_rcp(a1.y * kk.y + 1.0f);
            s2[1][l] += vv.z * fast_rcp(a1.z * kk.z + 1.0f);
            s2[1][l] += vv.w * fast_rcp(a1.w * kk.w + 1.0f);
        }
    }
    #pragma unroll
    for (int l = 0; l < 4; ++l) {
        sj_s[l][tid]       = vcsum - 2.0f * s2[0][l];
        sj_s[l][tid + 256] = vcsum - 2.0f * s2[1][l];
    }
    __syncthreads();

    // phase 2: softmax over q, wave w owns row l=w
    const int w = tid >> 6, lane = tid & 63;
    float m = -1e30f;
    #pragma unroll
    for (int i = 0; i < 8; ++i) m = fmaxf(m, sj_s[w][lane + 64 * i]);
    #pragma unroll
    for (int off = 32; off >= 1; off >>= 1) m = fmaxf(m, __shfl_xor(m, off));
    float Z = 0.f;
    #pragma unroll
    for (int i = 0; i < 8; ++i) {
        const float ex = __expf(sj_s[w][lane + 64 * i] - m);
        sj_s[w][lane + 64 * i] = ex;   // lane-exclusive slots
        Z += ex;
    }
    #pragma unroll
    for (int off = 32; off >= 1; off >>= 1) Z += __shfl_xor(Z, off);
    if (lane == 0) rinv_s[w] = fast_rcp(Z);
    __syncthreads();

    // phase 3: write atten (coalesced per l-row)
    #pragma unroll
    for (int qq = 0; qq < 2; ++qq) {
        const int q = tid + qq * 256;
        #pragma unroll
        for (int l = 0; l < 4; ++l)
            attn[(size_t)(b * LK + l0 + l) * LQ + q] = sj_s[l][q] * rinv_s[l];
    }
}

// K3: context[b,l,:] = sum_q atten[b,l,q] * value[b,q,:]
// block = (b, l-tile of 4); 4 q-groups x 64 d-threads (float4 per thread); LDS reduce.
// Overwrites the ctx region that held Eq/Ek -- safe, K2 already consumed them.
__global__ __launch_bounds__(256) void context_kernel(
    const float* __restrict__ attn, const float* __restrict__ value,
    float* __restrict__ ctx)
{
    const int b    = blockIdx.x >> 7;
    const int lt   = blockIdx.x & 127;
    const int row0 = b * LK + lt * 4;
    const int tid  = threadIdx.x;
    const int dth  = tid & 63;     // float4 chunk of d
    const int g    = tid >> 6;     // q-group
    const float4* v4 = (const float4*)(value + (size_t)b * LQ * DD);
    float ac[4][4];
    #pragma unroll
    for (int l = 0; l < 4; ++l) { ac[l][0]=0.f; ac[l][1]=0.f; ac[l][2]=0.f; ac[l][3]=0.f; }
    const int q0 = g * 128;
    for (int q = q0; q < q0 + 128; ++q) {
        const float4 v = v4[(size_t)q * 64 + dth];      // coalesced
        float al[4];
        #pragma unroll
        for (int l = 0; l < 4; ++l)
            al[l] = attn[(size_t)(row0 + l) * LQ + q];  // wave-uniform -> scalar loads
        #pragma unroll
        for (int l = 0; l < 4; ++l) {
            ac[l][0] += al[l] * v.x; ac[l][1] += al[l] * v.y;
            ac[l][2] += al[l] * v.z; ac[l][3] += al[l] * v.w;
        }
    }
    __shared__ float red[4][4][64][4];   // [g][l][dth][j] = 16 KiB
    #pragma unroll
    for (int l = 0; l < 4; ++l) {
        red[g][l][dth][0] = ac[l][0]; red[g][l][dth][1] = ac[l][1];
        red[g][l][dth][2] = ac[l][2]; red[g][l][dth][3] = ac[l][3];
    }
    __syncthreads();
    const int l  = tid >> 6;
    const int dt = tid & 63;
    float4 c;
    c.x = red[0][l][dt][0] + red[1][l][dt][0] + red[2][l][dt][0] + red[3][l][dt][0];
    c.y = red[0][l][dt][1] + red[1][l][dt][1] + red[2][l][dt][1] + red[3][l][dt][1];
    c.z = red[0][l][dt][2] + red[1][l][dt][2] + red[2][l][dt][2] + red[3][l][dt][2];
    c.w = red[0][l][dt][3] + red[1][l][dt][3] + red[2][l][dt][3] + red[3][l][dt][3];
    ((float4*)ctx)[(size_t)(row0 + l) * 64 + dt] = c;
}

extern "C" void kernel_launch(void* const* d_in, const int* in_sizes, int n_in,
                              void* d_out, int out_size, void* d_ws, size_t ws_size,
                              hipStream_t stream) {
    const float* query = (const float*)d_in[0];
    const float* key   = (const float*)d_in[1];
    const float* value = (const float*)d_in[2];
    const float* Wc1   = (const float*)d_in[3];
    const float* Wc2   = (const float*)d_in[4];
    const float* vc    = (const float*)d_in[5];

    float* ctx  = (float*)d_out;                          // [B, Lk, D]   = 524288 floats
    float* attn = (float*)d_out + (size_t)NB * LK * DD;   // [B, Lk, Lq]  = 1048576 floats

    // Scratch lives inside d_out's ctx region (exactly 2*NB*LQ*EE = 524288 floats).
    // K1 writes Eq/Ek there; K2 reads them and writes attn (disjoint);
    // K3 then overwrites the ctx region with the final context. No d_ws use.
    float* Eq = ctx;                                      // [B, Lq, E] = 262144 floats
    float* Ek = ctx + (size_t)NB * LQ * EE;               // [B, Lk, E] = 262144 floats

    proj_exp_kernel<<<dim3(512), dim3(256), 0, stream>>>(query, key, Wc1, Wc2, Eq, Ek);
    atten_kernel<<<dim3(NB * (LK / 4)), dim3(256), 0, stream>>>(Eq, Ek, vc, attn);
    context_kernel<<<dim3(NB * (LK / 4)), dim3(256), 0, stream>>>(attn, value, ctx);
}